// Round 7
// baseline (97.249 us; speedup 1.0000x reference)
//
#include <hip/hip_runtime.h>
#include <stdint.h>
#include <stddef.h>

#define BATCH 256
#define IN_F  4096
#define OUT_F 4096
#define KSPLIT 4

typedef __attribute__((ext_vector_type(8))) short    bf16x8;
typedef __attribute__((ext_vector_type(4))) float    f32x4;
typedef __attribute__((ext_vector_type(2))) uint32_t u32x2;
typedef __attribute__((ext_vector_type(4))) uint32_t u32x4;

#define MFMA(a,b,c) __builtin_amdgcn_mfma_f32_16x16x32_bf16((a),(b),(c),0,0,0)
#define HALF_LOG2E 0.7213475204444817f   // exp(0.5*x) == exp2(x*HALF_LOG2E)

__device__ __forceinline__ uint32_t pack2bf(float a, float b) {
  uint32_t ua = __builtin_bit_cast(uint32_t, a);
  uint32_t ub = __builtin_bit_cast(uint32_t, b);
  ua += 0x7FFFu + ((ua >> 16) & 1u);
  ub += 0x7FFFu + ((ub >> 16) & 1u);
  return (ua >> 16) | (ub & 0xFFFF0000u);
}

__device__ __forceinline__ bf16x8 cvt8(const float* p) {
  f32x4 v0 = *(const f32x4*)p;
  f32x4 v1 = *(const f32x4*)(p + 4);
  union { u32x4 u; bf16x8 h; } r;
  r.u[0] = pack2bf(v0[0], v0[1]); r.u[1] = pack2bf(v0[2], v0[3]);
  r.u[2] = pack2bf(v1[0], v1[1]); r.u[3] = pack2bf(v1[2], v1[3]);
  return r.h;
}

__device__ __forceinline__ void gload_lds16(const void* g, void* l) {
  __builtin_amdgcn_global_load_lds(
      (const __attribute__((address_space(1))) uint32_t*)g,
      (__attribute__((address_space(3))) uint32_t*)l, 16, 0, 0);
}

// non-temporal (no-allocate) vector load/store — the R7 single variable
__device__ __forceinline__ f32x4 ntld4(const float* p) {
  return __builtin_nontemporal_load((const f32x4*)p);
}
__device__ __forceinline__ void ntst4(void* p, u32x4 v) {
  __builtin_nontemporal_store(v, (u32x4*)p);
}

// ---------------------------------------------------------------------------
// Persistent streaming pass: W = mu + eps*exp(.5*lv) -> bf16 tile images
// (layout identical to R4-R6, validated); x -> bf16; bias.
// R7 change: ALL streaming loads/stores are non-temporal (no L2/L3
// allocation). Working set ~246 MB ~= L3 size -> allocating reads thrash
// the LLC at ~2.9 TB/s logical; nt path should stream at HBM rate.
// ---------------------------------------------------------------------------
#define WBLKP 1024   // persistent W blocks
#define UPB   8      // units per block (8192 units total)
#define XBLK  512    // x blocks: 512 x 2048 floats
#define HLG HALF_LOG2E

__global__ __launch_bounds__(256) void wcvt_persist(
    const float* __restrict__ wmu,
    const float* __restrict__ wlv,
    const float* __restrict__ weps,
    const float* __restrict__ x,
    const float* __restrict__ bmu,
    const float* __restrict__ blv,
    const float* __restrict__ beps,
    uint8_t*  __restrict__ wimg,
    uint8_t*  __restrict__ xs,
    float*    __restrict__ bias)
{
  const uint32_t b = blockIdx.x;
  const int      t = threadIdx.x;

  if (b < WBLKP) {
    // ---- persistent, pipelined W stream ----
    f32x4 am0, am1, av0, av1, ae0, ae1;    // set A
    f32x4 bm0, bm1, bv0, bv1, be0, be1;    // set B

#define GOFS(u) ((size_t)((u) >> 1) * 4096u + (size_t)((u) & 1) * 2048u + 8u * (uint32_t)t)
#define LOADS(M0,M1,V0,V1,E0,E1,u) do {                    \
    const size_t _o = GOFS(u);                             \
    M0 = ntld4(wmu  + _o); M1 = ntld4(wmu  + _o + 4);      \
    V0 = ntld4(wlv  + _o); V1 = ntld4(wlv  + _o + 4);      \
    E0 = ntld4(weps + _o); E1 = ntld4(weps + _o + 4);      \
  } while (0)
#define CONVST(M0,M1,V0,V1,E0,E1,u) do {                                   \
    u32x4 _o4;                                                             \
    _o4[0] = pack2bf(fmaf(E0[0], exp2f(V0[0]*HLG), M0[0]),                 \
                     fmaf(E0[1], exp2f(V0[1]*HLG), M0[1]));                \
    _o4[1] = pack2bf(fmaf(E0[2], exp2f(V0[2]*HLG), M0[2]),                 \
                     fmaf(E0[3], exp2f(V0[3]*HLG), M0[3]));                \
    _o4[2] = pack2bf(fmaf(E1[0], exp2f(V1[0]*HLG), M1[0]),                 \
                     fmaf(E1[1], exp2f(V1[1]*HLG), M1[1]));                \
    _o4[3] = pack2bf(fmaf(E1[2], exp2f(V1[2]*HLG), M1[2]),                 \
                     fmaf(E1[3], exp2f(V1[3]*HLG), M1[3]));                \
    const uint32_t _n  = (u) >> 1,  _h = (u) & 1;                          \
    const uint32_t _r  = _n & 15u,  _nt = _n >> 4;                         \
    const uint32_t _kt = _h * 16u + ((uint32_t)t >> 4);                    \
    const uint32_t _g  = (uint32_t)t & 15u;                                \
    ntst4(wimg + (((size_t)(_nt * 32u + _kt)) << 12)                       \
               + (_r << 8) + (((_g ^ _r) & 15u) << 4), _o4);               \
  } while (0)

    LOADS(am0, am1, av0, av1, ae0, ae1, b);        // prologue: unit 0 -> A
#pragma unroll
    for (int i = 0; i < UPB; ++i) {
      const uint32_t u  = b + (uint32_t)i * WBLKP;
      const uint32_t un = u + WBLKP;
      if ((i & 1) == 0) {
        if (i + 1 < UPB) LOADS(bm0, bm1, bv0, bv1, be0, be1, un);
        CONVST(am0, am1, av0, av1, ae0, ae1, u);
      } else {
        if (i + 1 < UPB) LOADS(am0, am1, av0, av1, ae0, ae1, un);
        CONVST(bm0, bm1, bv0, bv1, be0, be1, u);
      }
    }
#undef GOFS
#undef LOADS
#undef CONVST
  } else if (b < WBLKP + XBLK) {
    // ---- x -> bf16 ----
    const size_t o = (size_t)(b - WBLKP) * 2048u + 8u * (uint32_t)t;
    f32x4 x0 = ntld4(x + o);
    f32x4 x1 = ntld4(x + o + 4);
    u32x4 w;
    w[0] = pack2bf(x0[0], x0[1]); w[1] = pack2bf(x0[2], x0[3]);
    w[2] = pack2bf(x1[0], x1[1]); w[3] = pack2bf(x1[2], x1[3]);
    ntst4(xs + o * 2u, w);
  } else {
    // ---- bias ----
#pragma unroll
    for (int i = 0; i < 16; ++i) {
      const int j = i * 256 + t;
      bias[j] = fmaf(beps[j], exp2f(blv[j] * HLG), bmu[j]);
    }
  }
}

// ---------------------------------------------------------------------------
// Pass 2: y = xs @ W_bf16^T (+ bias if NSPLIT==1, else fp32 partials).
// (unchanged — validated)
// ---------------------------------------------------------------------------
template<int NSPLIT>
__global__ __launch_bounds__(256, 2)
void vgemm_img(const uint16_t* __restrict__ xs,
               const uint8_t*  __restrict__ wimg,
               const float*    __restrict__ biasp,
               float*          __restrict__ out)
{
  __shared__ __align__(16) uint8_t lds[16384];   // 2 bufs x 2 images x 4 KB

  const int tid = threadIdx.x;
  const int wv  = tid >> 6;
  const int l   = tid & 63;
  const int cg  = blockIdx.x / NSPLIT;
  const int ks  = blockIdx.x % NSPLIT;
  const int nt0 = cg * 2;
  const int KT0 = ks * (32 / NSPLIT);
  const int NIT = 32 / NSPLIT;

  const int br = l & 15;
  const int kb = l >> 4;
  const int arow0 = wv * 64 + br;

  f32x4 acc0[4] = {{0,0,0,0},{0,0,0,0},{0,0,0,0},{0,0,0,0}};
  f32x4 acc1[4] = {{0,0,0,0},{0,0,0,0},{0,0,0,0},{0,0,0,0}};

  auto STAGE = [&](int t, int buf) {
    const int kt = KT0 + t;
#pragma unroll
    for (int j = 0; j < 2; ++j) {
      const int ch = wv * 2 + j;
      const int i  = ch >> 2;
      const int q  = ch & 3;
      const uint8_t* src = wimg + (((size_t)((nt0 + i) * 32 + kt)) << 12)
                                + q * 1024 + l * 16;
      gload_lds16(src, &lds[0] + buf * 8192 + i * 4096 + q * 1024 + l * 16);
    }
  };

  auto COMP = [&](int t, int buf) {
    const uint8_t* B = &lds[0] + buf * 8192;
#pragma unroll
    for (int s = 0; s < 4; ++s) {
      const int swz = br * 256 + ((((s * 4 + kb) ^ br) & 15) << 4);
      bf16x8 b0 = *(const bf16x8*)(B + swz);
      bf16x8 b1 = *(const bf16x8*)(B + 4096 + swz);
      const size_t kk = (size_t)(KT0 + t) * 128 + s * 32 + kb * 8;
#pragma unroll
      for (int j = 0; j < 4; ++j) {
        bf16x8 a = *(const bf16x8*)(xs + (size_t)(arow0 + 16 * j) * IN_F + kk);
        acc0[j] = MFMA(a, b0, acc0[j]);
        acc1[j] = MFMA(a, b1, acc1[j]);
      }
    }
  };

  STAGE(0, 0);
  for (int t = 0; t < NIT; ++t) {
    if (t + 1 < NIT) STAGE(t + 1, (t + 1) & 1);
    __syncthreads();
    COMP(t, t & 1);
    __syncthreads();
  }

#pragma unroll
  for (int img = 0; img < 2; ++img) {
    const f32x4* acc = img ? acc1 : acc0;
    const int col = cg * 32 + img * 16 + br;
    if constexpr (NSPLIT == 1) {
      const float bv = biasp[col];
#pragma unroll
      for (int j = 0; j < 4; ++j) {
        const int rbase = wv * 64 + j * 16 + kb * 4;
#pragma unroll
        for (int i = 0; i < 4; ++i)
          out[(size_t)(rbase + i) * OUT_F + col] = acc[j][i] + bv;
      }
    } else {
      float* po = out + (size_t)ks * BATCH * OUT_F;
#pragma unroll
      for (int j = 0; j < 4; ++j) {
        const int rbase = wv * 64 + j * 16 + kb * 4;
#pragma unroll
        for (int i = 0; i < 4; ++i)
          po[(size_t)(rbase + i) * OUT_F + col] = acc[j][i];
      }
    }
  }
}

// ---------------------------------------------------------------------------
// Fallback prep + fused GEMM (R3 structure) for degraded ws sizes.
// ---------------------------------------------------------------------------
__global__ __launch_bounds__(256) void prep_kernel(
    const float* __restrict__ x,
    const float* __restrict__ bmu,
    const float* __restrict__ blv,
    const float* __restrict__ beps,
    u32x4* __restrict__ xs4,
    float* __restrict__ bias)
{
  const uint32_t b = blockIdx.x;
  if (b < 512u) {
    const uint32_t c = b * 256u + threadIdx.x;
    const float* p = x + (size_t)c * 8u;
    f32x4 v0 = *(const f32x4*)p;
    f32x4 v1 = *(const f32x4*)(p + 4);
    u32x4 o;
    o[0] = pack2bf(v0[0], v0[1]); o[1] = pack2bf(v0[2], v0[3]);
    o[2] = pack2bf(v1[0], v1[1]); o[3] = pack2bf(v1[2], v1[3]);
    xs4[c] = o;
  } else {
    const uint32_t i = (b - 512u) * 256u + threadIdx.x;
    bias[i] = fmaf(beps[i], exp2f(blv[i] * HALF_LOG2E), bmu[i]);
  }
}

#define RAW_BUF   12288
#define RAW_ARR   4096
#define BF_BASE   24576
#define LDS_TOTAL 26624

template<int NSPLIT, bool USE_XS>
__global__ __launch_bounds__(256, 4)
void vgemm3(const uint16_t* __restrict__ xs,
            const float*    __restrict__ xf,
            const float*    __restrict__ wmu,
            const float*    __restrict__ wlv,
            const float*    __restrict__ weps,
            const float*    __restrict__ biasp,
            const float*    __restrict__ bmu,
            const float*    __restrict__ blv,
            const float*    __restrict__ beps,
            float*          __restrict__ out)
{
  __shared__ __align__(16) uint8_t lds[LDS_TOTAL];

  const int tid = threadIdx.x;
  const int wv  = tid >> 6;
  const int l   = tid & 63;
  const int col_tile = blockIdx.x / NSPLIT;
  const int ks       = blockIdx.x % NSPLIT;
  const int n0  = col_tile * 16;
  const int k0  = ks * (IN_F / NSPLIT);
  const int NT  = (IN_F / NSPLIT) / 64;

  const size_t sgoff = (size_t)(n0 + 4 * wv + (l >> 4)) * IN_F + k0 + ((l & 15) << 2);
  const int cr = tid >> 4;
  const int ci = tid & 15;
  const int bfw = cr * 128 + ((((ci >> 1) ^ (cr & 7)) << 4)) + ((ci & 1) << 3);
  const int br = l & 15;
  const int kb = l >> 4;
  const int bfo0 = br * 128 + ((((0 * 4 + kb)) ^ (br & 7)) << 4);
  const int bfo1 = br * 128 + ((((1 * 4 + kb)) ^ (br & 7)) << 4);
  const int arow0 = wv * 64 + br;

  f32x4 acc[4] = {{0,0,0,0},{0,0,0,0},{0,0,0,0},{0,0,0,0}};

  auto STAGE = [&](int t, int buf) {
    const size_t go = sgoff + (size_t)t * 64;
    uint8_t* base = &lds[0] + buf * RAW_BUF + wv * 1024;
    gload_lds16(wmu  + go, base + 0 * RAW_ARR);
    gload_lds16(wlv  + go, base + 1 * RAW_ARR);
    gload_lds16(weps + go, base + 2 * RAW_ARR);
  };
  auto CVT = [&](int buf) {
    const uint8_t* rb = &lds[0] + buf * RAW_BUF;
    f32x4 m = *(const f32x4*)(rb + 0 * RAW_ARR + tid * 16);
    f32x4 v = *(const f32x4*)(rb + 1 * RAW_ARR + tid * 16);
    f32x4 e = *(const f32x4*)(rb + 2 * RAW_ARR + tid * 16);
    u32x2 o;
    o[0] = pack2bf(fmaf(e[0], exp2f(v[0] * HALF_LOG2E), m[0]),
                   fmaf(e[1], exp2f(v[1] * HALF_LOG2E), m[1]));
    o[1] = pack2bf(fmaf(e[2], exp2f(v[2] * HALF_LOG2E), m[2]),
                   fmaf(e[3], exp2f(v[3] * HALF_LOG2E), m[3]));
    *(u32x2*)(&lds[0] + BF_BASE + bfw) = o;
  };
  auto COMP = [&](int t) {
    const uint8_t* bfb = &lds[0] + BF_BASE;
    bf16x8 b0 = *(const bf16x8*)(bfb + bfo0);
    bf16x8 b1 = *(const bf16x8*)(bfb + bfo1);
    const size_t kb0 = (size_t)k0 + t * 64 + kb * 8;
#pragma unroll
    for (int j = 0; j < 4; ++j) {
      bf16x8 a0, a1;
      if constexpr (USE_XS) {
        const uint16_t* xp = xs + (size_t)(arow0 + 16 * j) * IN_F + kb0;
        a0 = *(const bf16x8*)(xp);
        a1 = *(const bf16x8*)(xp + 32);
      } else {
        const float* xp = xf + (size_t)(arow0 + 16 * j) * IN_F + kb0;
        a0 = cvt8(xp);
        a1 = cvt8(xp + 32);
      }
      acc[j] = MFMA(a0, b0, acc[j]);
      acc[j] = MFMA(a1, b1, acc[j]);
    }
  };

  STAGE(0, 0);
  for (int t = 0; t < NT; ++t) {
    if (t + 1 < NT) STAGE(t + 1, (t + 1) & 1);
    __syncthreads();
    CVT(t & 1);
    __syncthreads();
    COMP(t);
  }

  const int col = n0 + br;
  if constexpr (NSPLIT == 1) {
    float bv;
    if constexpr (USE_XS) bv = biasp[col];
    else bv = fmaf(beps[col], exp2f(blv[col] * HALF_LOG2E), bmu[col]);
#pragma unroll
    for (int j = 0; j < 4; ++j) {
      const int rbase = wv * 64 + j * 16 + kb * 4;
#pragma unroll
      for (int i = 0; i < 4; ++i)
        out[(size_t)(rbase + i) * OUT_F + col] = acc[j][i] + bv;
    }
  } else {
    float* po = out + (size_t)ks * BATCH * OUT_F;
#pragma unroll
    for (int j = 0; j < 4; ++j) {
      const int rbase = wv * 64 + j * 16 + kb * 4;
#pragma unroll
      for (int i = 0; i < 4; ++i)
        po[(size_t)(rbase + i) * OUT_F + col] = acc[j][i];
    }
  }
}

// ---------------------------------------------------------------------------
__global__ __launch_bounds__(256) void reduce_kernel(
    const float* __restrict__ parts,
    const float* __restrict__ bias,
    float* __restrict__ y)
{
  const size_t e = ((size_t)blockIdx.x * 256 + threadIdx.x) * 4;
  f32x4 s = *(const f32x4*)(parts + e);
#pragma unroll
  for (int p = 1; p < KSPLIT; ++p)
    s += *(const f32x4*)(parts + (size_t)p * BATCH * OUT_F + e);
  s += *(const f32x4*)(bias + (e & (OUT_F - 1)));
  *(f32x4*)(y + e) = s;
}

// ---------------------------------------------------------------------------
extern "C" void kernel_launch(void* const* d_in, const int* in_sizes, int n_in,
                              void* d_out, int out_size, void* d_ws, size_t ws_size,
                              hipStream_t stream) {
  const float* x    = (const float*)d_in[0];
  const float* wmu  = (const float*)d_in[1];
  const float* wlv  = (const float*)d_in[2];
  const float* bmu  = (const float*)d_in[3];
  const float* blv  = (const float*)d_in[4];
  const float* weps = (const float*)d_in[5];
  const float* beps = (const float*)d_in[6];
  float* y = (float*)d_out;

  const size_t xs_b   = (size_t)BATCH * IN_F * 2;            // 2 MiB
  const size_t bias_b = (size_t)OUT_F * 4;                   // 16 KiB
  const size_t part_b = (size_t)KSPLIT * BATCH * OUT_F * 4;  // 16 MiB
  const size_t img_b  = (size_t)OUT_F * IN_F * 2;            // 32 MiB

  uint16_t* xsp  = (uint16_t*)d_ws;
  float*    bias = (float*)((char*)d_ws + xs_b);

  if (d_ws && ws_size >= xs_b + bias_b + part_b + img_b) {
    float*   parts = (float*)((char*)d_ws + xs_b + bias_b);
    uint8_t* wimg  = (uint8_t*)d_ws + xs_b + bias_b + part_b;
    wcvt_persist<<<WBLKP + XBLK + 1, 256, 0, stream>>>(
        wmu, wlv, weps, x, bmu, blv, beps, wimg, (uint8_t*)xsp, bias);
    vgemm_img<KSPLIT><<<(OUT_F / 32) * KSPLIT, 256, 0, stream>>>(xsp, wimg, bias, parts);
    reduce_kernel<<<(BATCH * OUT_F) / (256 * 4), 256, 0, stream>>>(parts, bias, y);
  } else if (d_ws && ws_size >= xs_b + bias_b + img_b) {
    uint8_t* wimg = (uint8_t*)d_ws + xs_b + bias_b;
    wcvt_persist<<<WBLKP + XBLK + 1, 256, 0, stream>>>(
        wmu, wlv, weps, x, bmu, blv, beps, wimg, (uint8_t*)xsp, bias);
    vgemm_img<1><<<OUT_F / 32, 256, 0, stream>>>(xsp, wimg, bias, y);
  } else if (d_ws && ws_size >= xs_b + bias_b + part_b) {
    float* parts = (float*)((char*)d_ws + xs_b + bias_b);
    prep_kernel<<<528, 256, 0, stream>>>(x, bmu, blv, beps, (u32x4*)d_ws, bias);
    vgemm3<KSPLIT, true><<<(OUT_F / 16) * KSPLIT, 256, 0, stream>>>(
        xsp, nullptr, wmu, wlv, weps, bias, nullptr, nullptr, nullptr, parts);
    reduce_kernel<<<(BATCH * OUT_F) / (256 * 4), 256, 0, stream>>>(parts, bias, y);
  } else if (d_ws && ws_size >= xs_b + bias_b) {
    prep_kernel<<<528, 256, 0, stream>>>(x, bmu, blv, beps, (u32x4*)d_ws, bias);
    vgemm3<1, true><<<OUT_F / 16, 256, 0, stream>>>(
        xsp, nullptr, wmu, wlv, weps, bias, nullptr, nullptr, nullptr, y);
  } else {
    vgemm3<1, false><<<OUT_F / 16, 256, 0, stream>>>(
        nullptr, x, wmu, wlv, weps, nullptr, bmu, blv, beps, y);
  }
}

// Round 8
// 96.003 us; speedup vs baseline: 1.0130x; 1.0130x over previous
//
#include <hip/hip_runtime.h>
#include <stdint.h>
#include <stddef.h>

#define BATCH 256
#define IN_F  4096
#define OUT_F 4096
#define KSPLIT 4

typedef __attribute__((ext_vector_type(8))) short    bf16x8;
typedef __attribute__((ext_vector_type(4))) float    f32x4;
typedef __attribute__((ext_vector_type(2))) uint32_t u32x2;
typedef __attribute__((ext_vector_type(4))) uint32_t u32x4;

#define MFMA(a,b,c) __builtin_amdgcn_mfma_f32_16x16x32_bf16((a),(b),(c),0,0,0)
#define HALF_LOG2E 0.7213475204444817f   // exp(0.5*x) == exp2(x*HALF_LOG2E)

__device__ __forceinline__ uint32_t pack2bf(float a, float b) {
  uint32_t ua = __builtin_bit_cast(uint32_t, a);
  uint32_t ub = __builtin_bit_cast(uint32_t, b);
  ua += 0x7FFFu + ((ua >> 16) & 1u);
  ub += 0x7FFFu + ((ub >> 16) & 1u);
  return (ua >> 16) | (ub & 0xFFFF0000u);
}

__device__ __forceinline__ bf16x8 cvt8(const float* p) {
  f32x4 v0 = *(const f32x4*)p;
  f32x4 v1 = *(const f32x4*)(p + 4);
  union { u32x4 u; bf16x8 h; } r;
  r.u[0] = pack2bf(v0[0], v0[1]); r.u[1] = pack2bf(v0[2], v0[3]);
  r.u[2] = pack2bf(v1[0], v1[1]); r.u[3] = pack2bf(v1[2], v1[3]);
  return r.h;
}

__device__ __forceinline__ void gload_lds16(const void* g, void* l) {
  __builtin_amdgcn_global_load_lds(
      (const __attribute__((address_space(1))) uint32_t*)g,
      (__attribute__((address_space(3))) uint32_t*)l, 16, 0, 0);
}

// non-temporal (no-allocate) READS for the 192 MB once-used input stream.
// Stores are NORMAL (allocating): wimg/xs are producer->consumer ws data
// that pass 2 must find in L2/L3 (R7 lesson: nt stores cost e2e +15us).
__device__ __forceinline__ f32x4 ntld4(const float* p) {
  return __builtin_nontemporal_load((const f32x4*)p);
}

// ---------------------------------------------------------------------------
// Persistent streaming pass: W = mu + eps*exp(.5*lv) -> bf16 tile images
// (layout identical to R4-R7, validated); x -> bf16; bias.
// nt loads (no LLC allocation for the 192 MB stream), normal stores.
// ---------------------------------------------------------------------------
#define WBLKP 1024   // persistent W blocks
#define UPB   8      // units per block (8192 units total)
#define XBLK  512    // x blocks: 512 x 2048 floats
#define HLG HALF_LOG2E

__global__ __launch_bounds__(256) void wcvt_persist(
    const float* __restrict__ wmu,
    const float* __restrict__ wlv,
    const float* __restrict__ weps,
    const float* __restrict__ x,
    const float* __restrict__ bmu,
    const float* __restrict__ blv,
    const float* __restrict__ beps,
    uint8_t*  __restrict__ wimg,
    uint8_t*  __restrict__ xs,
    float*    __restrict__ bias)
{
  const uint32_t b = blockIdx.x;
  const int      t = threadIdx.x;

  if (b < WBLKP) {
    // ---- persistent, pipelined W stream ----
    f32x4 am0, am1, av0, av1, ae0, ae1;    // set A
    f32x4 bm0, bm1, bv0, bv1, be0, be1;    // set B

#define GOFS(u) ((size_t)((u) >> 1) * 4096u + (size_t)((u) & 1) * 2048u + 8u * (uint32_t)t)
#define LOADS(M0,M1,V0,V1,E0,E1,u) do {                    \
    const size_t _o = GOFS(u);                             \
    M0 = ntld4(wmu  + _o); M1 = ntld4(wmu  + _o + 4);      \
    V0 = ntld4(wlv  + _o); V1 = ntld4(wlv  + _o + 4);      \
    E0 = ntld4(weps + _o); E1 = ntld4(weps + _o + 4);      \
  } while (0)
#define CONVST(M0,M1,V0,V1,E0,E1,u) do {                                   \
    u32x4 _o4;                                                             \
    _o4[0] = pack2bf(fmaf(E0[0], exp2f(V0[0]*HLG), M0[0]),                 \
                     fmaf(E0[1], exp2f(V0[1]*HLG), M0[1]));                \
    _o4[1] = pack2bf(fmaf(E0[2], exp2f(V0[2]*HLG), M0[2]),                 \
                     fmaf(E0[3], exp2f(V0[3]*HLG), M0[3]));                \
    _o4[2] = pack2bf(fmaf(E1[0], exp2f(V1[0]*HLG), M1[0]),                 \
                     fmaf(E1[1], exp2f(V1[1]*HLG), M1[1]));                \
    _o4[3] = pack2bf(fmaf(E1[2], exp2f(V1[2]*HLG), M1[2]),                 \
                     fmaf(E1[3], exp2f(V1[3]*HLG), M1[3]));                \
    const uint32_t _n  = (u) >> 1,  _h = (u) & 1;                          \
    const uint32_t _r  = _n & 15u,  _nt = _n >> 4;                         \
    const uint32_t _kt = _h * 16u + ((uint32_t)t >> 4);                    \
    const uint32_t _g  = (uint32_t)t & 15u;                                \
    *(u32x4*)(wimg + (((size_t)(_nt * 32u + _kt)) << 12)                   \
                   + (_r << 8) + (((_g ^ _r) & 15u) << 4)) = _o4;          \
  } while (0)

    LOADS(am0, am1, av0, av1, ae0, ae1, b);        // prologue: unit 0 -> A
#pragma unroll
    for (int i = 0; i < UPB; ++i) {
      const uint32_t u  = b + (uint32_t)i * WBLKP;
      const uint32_t un = u + WBLKP;
      if ((i & 1) == 0) {
        if (i + 1 < UPB) LOADS(bm0, bm1, bv0, bv1, be0, be1, un);
        CONVST(am0, am1, av0, av1, ae0, ae1, u);
      } else {
        if (i + 1 < UPB) LOADS(am0, am1, av0, av1, ae0, ae1, un);
        CONVST(bm0, bm1, bv0, bv1, be0, be1, u);
      }
    }
#undef GOFS
#undef LOADS
#undef CONVST
  } else if (b < WBLKP + XBLK) {
    // ---- x -> bf16 ----
    const size_t o = (size_t)(b - WBLKP) * 2048u + 8u * (uint32_t)t;
    f32x4 x0 = ntld4(x + o);
    f32x4 x1 = ntld4(x + o + 4);
    u32x4 w;
    w[0] = pack2bf(x0[0], x0[1]); w[1] = pack2bf(x0[2], x0[3]);
    w[2] = pack2bf(x1[0], x1[1]); w[3] = pack2bf(x1[2], x1[3]);
    *(u32x4*)(xs + o * 2u) = w;
  } else {
    // ---- bias ----
#pragma unroll
    for (int i = 0; i < 16; ++i) {
      const int j = i * 256 + t;
      bias[j] = fmaf(beps[j], exp2f(blv[j] * HLG), bmu[j]);
    }
  }
}

// ---------------------------------------------------------------------------
// Pass 2: y = xs @ W_bf16^T (+ bias if NSPLIT==1, else fp32 partials).
// (unchanged — validated)
// ---------------------------------------------------------------------------
template<int NSPLIT>
__global__ __launch_bounds__(256, 2)
void vgemm_img(const uint16_t* __restrict__ xs,
               const uint8_t*  __restrict__ wimg,
               const float*    __restrict__ biasp,
               float*          __restrict__ out)
{
  __shared__ __align__(16) uint8_t lds[16384];   // 2 bufs x 2 images x 4 KB

  const int tid = threadIdx.x;
  const int wv  = tid >> 6;
  const int l   = tid & 63;
  const int cg  = blockIdx.x / NSPLIT;
  const int ks  = blockIdx.x % NSPLIT;
  const int nt0 = cg * 2;
  const int KT0 = ks * (32 / NSPLIT);
  const int NIT = 32 / NSPLIT;

  const int br = l & 15;
  const int kb = l >> 4;
  const int arow0 = wv * 64 + br;

  f32x4 acc0[4] = {{0,0,0,0},{0,0,0,0},{0,0,0,0},{0,0,0,0}};
  f32x4 acc1[4] = {{0,0,0,0},{0,0,0,0},{0,0,0,0},{0,0,0,0}};

  auto STAGE = [&](int t, int buf) {
    const int kt = KT0 + t;
#pragma unroll
    for (int j = 0; j < 2; ++j) {
      const int ch = wv * 2 + j;
      const int i  = ch >> 2;
      const int q  = ch & 3;
      const uint8_t* src = wimg + (((size_t)((nt0 + i) * 32 + kt)) << 12)
                                + q * 1024 + l * 16;
      gload_lds16(src, &lds[0] + buf * 8192 + i * 4096 + q * 1024 + l * 16);
    }
  };

  auto COMP = [&](int t, int buf) {
    const uint8_t* B = &lds[0] + buf * 8192;
#pragma unroll
    for (int s = 0; s < 4; ++s) {
      const int swz = br * 256 + ((((s * 4 + kb) ^ br) & 15) << 4);
      bf16x8 b0 = *(const bf16x8*)(B + swz);
      bf16x8 b1 = *(const bf16x8*)(B + 4096 + swz);
      const size_t kk = (size_t)(KT0 + t) * 128 + s * 32 + kb * 8;
#pragma unroll
      for (int j = 0; j < 4; ++j) {
        bf16x8 a = *(const bf16x8*)(xs + (size_t)(arow0 + 16 * j) * IN_F + kk);
        acc0[j] = MFMA(a, b0, acc0[j]);
        acc1[j] = MFMA(a, b1, acc1[j]);
      }
    }
  };

  STAGE(0, 0);
  for (int t = 0; t < NIT; ++t) {
    if (t + 1 < NIT) STAGE(t + 1, (t + 1) & 1);
    __syncthreads();
    COMP(t, t & 1);
    __syncthreads();
  }

#pragma unroll
  for (int img = 0; img < 2; ++img) {
    const f32x4* acc = img ? acc1 : acc0;
    const int col = cg * 32 + img * 16 + br;
    if constexpr (NSPLIT == 1) {
      const float bv = biasp[col];
#pragma unroll
      for (int j = 0; j < 4; ++j) {
        const int rbase = wv * 64 + j * 16 + kb * 4;
#pragma unroll
        for (int i = 0; i < 4; ++i)
          out[(size_t)(rbase + i) * OUT_F + col] = acc[j][i] + bv;
      }
    } else {
      float* po = out + (size_t)ks * BATCH * OUT_F;
#pragma unroll
      for (int j = 0; j < 4; ++j) {
        const int rbase = wv * 64 + j * 16 + kb * 4;
#pragma unroll
        for (int i = 0; i < 4; ++i)
          po[(size_t)(rbase + i) * OUT_F + col] = acc[j][i];
      }
    }
  }
}

// ---------------------------------------------------------------------------
// Fallback prep + fused GEMM (R3 structure) for degraded ws sizes.
// ---------------------------------------------------------------------------
__global__ __launch_bounds__(256) void prep_kernel(
    const float* __restrict__ x,
    const float* __restrict__ bmu,
    const float* __restrict__ blv,
    const float* __restrict__ beps,
    u32x4* __restrict__ xs4,
    float* __restrict__ bias)
{
  const uint32_t b = blockIdx.x;
  if (b < 512u) {
    const uint32_t c = b * 256u + threadIdx.x;
    const float* p = x + (size_t)c * 8u;
    f32x4 v0 = *(const f32x4*)p;
    f32x4 v1 = *(const f32x4*)(p + 4);
    u32x4 o;
    o[0] = pack2bf(v0[0], v0[1]); o[1] = pack2bf(v0[2], v0[3]);
    o[2] = pack2bf(v1[0], v1[1]); o[3] = pack2bf(v1[2], v1[3]);
    xs4[c] = o;
  } else {
    const uint32_t i = (b - 512u) * 256u + threadIdx.x;
    bias[i] = fmaf(beps[i], exp2f(blv[i] * HALF_LOG2E), bmu[i]);
  }
}

#define RAW_BUF   12288
#define RAW_ARR   4096
#define BF_BASE   24576
#define LDS_TOTAL 26624

template<int NSPLIT, bool USE_XS>
__global__ __launch_bounds__(256, 4)
void vgemm3(const uint16_t* __restrict__ xs,
            const float*    __restrict__ xf,
            const float*    __restrict__ wmu,
            const float*    __restrict__ wlv,
            const float*    __restrict__ weps,
            const float*    __restrict__ biasp,
            const float*    __restrict__ bmu,
            const float*    __restrict__ blv,
            const float*    __restrict__ beps,
            float*          __restrict__ out)
{
  __shared__ __align__(16) uint8_t lds[LDS_TOTAL];

  const int tid = threadIdx.x;
  const int wv  = tid >> 6;
  const int l   = tid & 63;
  const int col_tile = blockIdx.x / NSPLIT;
  const int ks       = blockIdx.x % NSPLIT;
  const int n0  = col_tile * 16;
  const int k0  = ks * (IN_F / NSPLIT);
  const int NT  = (IN_F / NSPLIT) / 64;

  const size_t sgoff = (size_t)(n0 + 4 * wv + (l >> 4)) * IN_F + k0 + ((l & 15) << 2);
  const int cr = tid >> 4;
  const int ci = tid & 15;
  const int bfw = cr * 128 + ((((ci >> 1) ^ (cr & 7)) << 4)) + ((ci & 1) << 3);
  const int br = l & 15;
  const int kb = l >> 4;
  const int bfo0 = br * 128 + ((((0 * 4 + kb)) ^ (br & 7)) << 4);
  const int bfo1 = br * 128 + ((((1 * 4 + kb)) ^ (br & 7)) << 4);
  const int arow0 = wv * 64 + br;

  f32x4 acc[4] = {{0,0,0,0},{0,0,0,0},{0,0,0,0},{0,0,0,0}};

  auto STAGE = [&](int t, int buf) {
    const size_t go = sgoff + (size_t)t * 64;
    uint8_t* base = &lds[0] + buf * RAW_BUF + wv * 1024;
    gload_lds16(wmu  + go, base + 0 * RAW_ARR);
    gload_lds16(wlv  + go, base + 1 * RAW_ARR);
    gload_lds16(weps + go, base + 2 * RAW_ARR);
  };
  auto CVT = [&](int buf) {
    const uint8_t* rb = &lds[0] + buf * RAW_BUF;
    f32x4 m = *(const f32x4*)(rb + 0 * RAW_ARR + tid * 16);
    f32x4 v = *(const f32x4*)(rb + 1 * RAW_ARR + tid * 16);
    f32x4 e = *(const f32x4*)(rb + 2 * RAW_ARR + tid * 16);
    u32x2 o;
    o[0] = pack2bf(fmaf(e[0], exp2f(v[0] * HALF_LOG2E), m[0]),
                   fmaf(e[1], exp2f(v[1] * HALF_LOG2E), m[1]));
    o[1] = pack2bf(fmaf(e[2], exp2f(v[2] * HALF_LOG2E), m[2]),
                   fmaf(e[3], exp2f(v[3] * HALF_LOG2E), m[3]));
    *(u32x2*)(&lds[0] + BF_BASE + bfw) = o;
  };
  auto COMP = [&](int t) {
    const uint8_t* bfb = &lds[0] + BF_BASE;
    bf16x8 b0 = *(const bf16x8*)(bfb + bfo0);
    bf16x8 b1 = *(const bf16x8*)(bfb + bfo1);
    const size_t kb0 = (size_t)k0 + t * 64 + kb * 8;
#pragma unroll
    for (int j = 0; j < 4; ++j) {
      bf16x8 a0, a1;
      if constexpr (USE_XS) {
        const uint16_t* xp = xs + (size_t)(arow0 + 16 * j) * IN_F + kb0;
        a0 = *(const bf16x8*)(xp);
        a1 = *(const bf16x8*)(xp + 32);
      } else {
        const float* xp = xf + (size_t)(arow0 + 16 * j) * IN_F + kb0;
        a0 = cvt8(xp);
        a1 = cvt8(xp + 32);
      }
      acc[j] = MFMA(a0, b0, acc[j]);
      acc[j] = MFMA(a1, b1, acc[j]);
    }
  };

  STAGE(0, 0);
  for (int t = 0; t < NT; ++t) {
    if (t + 1 < NT) STAGE(t + 1, (t + 1) & 1);
    __syncthreads();
    CVT(t & 1);
    __syncthreads();
    COMP(t);
  }

  const int col = n0 + br;
  if constexpr (NSPLIT == 1) {
    float bv;
    if constexpr (USE_XS) bv = biasp[col];
    else bv = fmaf(beps[col], exp2f(blv[col] * HALF_LOG2E), bmu[col]);
#pragma unroll
    for (int j = 0; j < 4; ++j) {
      const int rbase = wv * 64 + j * 16 + kb * 4;
#pragma unroll
      for (int i = 0; i < 4; ++i)
        out[(size_t)(rbase + i) * OUT_F + col] = acc[j][i] + bv;
    }
  } else {
    float* po = out + (size_t)ks * BATCH * OUT_F;
#pragma unroll
    for (int j = 0; j < 4; ++j) {
      const int rbase = wv * 64 + j * 16 + kb * 4;
#pragma unroll
      for (int i = 0; i < 4; ++i)
        po[(size_t)(rbase + i) * OUT_F + col] = acc[j][i];
    }
  }
}

// ---------------------------------------------------------------------------
__global__ __launch_bounds__(256) void reduce_kernel(
    const float* __restrict__ parts,
    const float* __restrict__ bias,
    float* __restrict__ y)
{
  const size_t e = ((size_t)blockIdx.x * 256 + threadIdx.x) * 4;
  f32x4 s = *(const f32x4*)(parts + e);
#pragma unroll
  for (int p = 1; p < KSPLIT; ++p)
    s += *(const f32x4*)(parts + (size_t)p * BATCH * OUT_F + e);
  s += *(const f32x4*)(bias + (e & (OUT_F - 1)));
  *(f32x4*)(y + e) = s;
}

// ---------------------------------------------------------------------------
extern "C" void kernel_launch(void* const* d_in, const int* in_sizes, int n_in,
                              void* d_out, int out_size, void* d_ws, size_t ws_size,
                              hipStream_t stream) {
  const float* x    = (const float*)d_in[0];
  const float* wmu  = (const float*)d_in[1];
  const float* wlv  = (const float*)d_in[2];
  const float* bmu  = (const float*)d_in[3];
  const float* blv  = (const float*)d_in[4];
  const float* weps = (const float*)d_in[5];
  const float* beps = (const float*)d_in[6];
  float* y = (float*)d_out;

  const size_t xs_b   = (size_t)BATCH * IN_F * 2;            // 2 MiB
  const size_t bias_b = (size_t)OUT_F * 4;                   // 16 KiB
  const size_t part_b = (size_t)KSPLIT * BATCH * OUT_F * 4;  // 16 MiB
  const size_t img_b  = (size_t)OUT_F * IN_F * 2;            // 32 MiB

  uint16_t* xsp  = (uint16_t*)d_ws;
  float*    bias = (float*)((char*)d_ws + xs_b);

  if (d_ws && ws_size >= xs_b + bias_b + part_b + img_b) {
    float*   parts = (float*)((char*)d_ws + xs_b + bias_b);
    uint8_t* wimg  = (uint8_t*)d_ws + xs_b + bias_b + part_b;
    wcvt_persist<<<WBLKP + XBLK + 1, 256, 0, stream>>>(
        wmu, wlv, weps, x, bmu, blv, beps, wimg, (uint8_t*)xsp, bias);
    vgemm_img<KSPLIT><<<(OUT_F / 32) * KSPLIT, 256, 0, stream>>>(xsp, wimg, bias, parts);
    reduce_kernel<<<(BATCH * OUT_F) / (256 * 4), 256, 0, stream>>>(parts, bias, y);
  } else if (d_ws && ws_size >= xs_b + bias_b + img_b) {
    uint8_t* wimg = (uint8_t*)d_ws + xs_b + bias_b;
    wcvt_persist<<<WBLKP + XBLK + 1, 256, 0, stream>>>(
        wmu, wlv, weps, x, bmu, blv, beps, wimg, (uint8_t*)xsp, bias);
    vgemm_img<1><<<OUT_F / 32, 256, 0, stream>>>(xsp, wimg, bias, y);
  } else if (d_ws && ws_size >= xs_b + bias_b + part_b) {
    float* parts = (float*)((char*)d_ws + xs_b + bias_b);
    prep_kernel<<<528, 256, 0, stream>>>(x, bmu, blv, beps, (u32x4*)d_ws, bias);
    vgemm3<KSPLIT, true><<<(OUT_F / 16) * KSPLIT, 256, 0, stream>>>(
        xsp, nullptr, wmu, wlv, weps, bias, nullptr, nullptr, nullptr, parts);
    reduce_kernel<<<(BATCH * OUT_F) / (256 * 4), 256, 0, stream>>>(parts, bias, y);
  } else if (d_ws && ws_size >= xs_b + bias_b) {
    prep_kernel<<<528, 256, 0, stream>>>(x, bmu, blv, beps, (u32x4*)d_ws, bias);
    vgemm3<1, true><<<OUT_F / 16, 256, 0, stream>>>(
        xsp, nullptr, wmu, wlv, weps, bias, nullptr, nullptr, nullptr, y);
  } else {
    vgemm3<1, false><<<OUT_F / 16, 256, 0, stream>>>(
        nullptr, x, wmu, wlv, weps, nullptr, bmu, blv, beps, y);
  }
}

// Round 9
// 94.910 us; speedup vs baseline: 1.0246x; 1.0115x over previous
//
#include <hip/hip_runtime.h>
#include <stdint.h>
#include <stddef.h>

#define BATCH 256
#define IN_F  4096
#define OUT_F 4096
#define KSPLIT 4

typedef __attribute__((ext_vector_type(8))) short    bf16x8;
typedef __attribute__((ext_vector_type(4))) float    f32x4;
typedef __attribute__((ext_vector_type(2))) uint32_t u32x2;
typedef __attribute__((ext_vector_type(4))) uint32_t u32x4;

#define MFMA(a,b,c) __builtin_amdgcn_mfma_f32_16x16x32_bf16((a),(b),(c),0,0,0)
#define HALF_LOG2E 0.7213475204444817f   // exp(0.5*x) == exp2(x*HALF_LOG2E)
#define HLG HALF_LOG2E

__device__ __forceinline__ uint32_t pack2bf(float a, float b) {
  uint32_t ua = __builtin_bit_cast(uint32_t, a);
  uint32_t ub = __builtin_bit_cast(uint32_t, b);
  ua += 0x7FFFu + ((ua >> 16) & 1u);
  ub += 0x7FFFu + ((ub >> 16) & 1u);
  return (ua >> 16) | (ub & 0xFFFF0000u);
}

__device__ __forceinline__ bf16x8 cvt8(const float* p) {
  f32x4 v0 = *(const f32x4*)p;
  f32x4 v1 = *(const f32x4*)(p + 4);
  union { u32x4 u; bf16x8 h; } r;
  r.u[0] = pack2bf(v0[0], v0[1]); r.u[1] = pack2bf(v0[2], v0[3]);
  r.u[2] = pack2bf(v1[0], v1[1]); r.u[3] = pack2bf(v1[2], v1[3]);
  return r.h;
}

__device__ __forceinline__ void gload_lds16(const void* g, void* l) {
  __builtin_amdgcn_global_load_lds(
      (const __attribute__((address_space(1))) uint32_t*)g,
      (__attribute__((address_space(3))) uint32_t*)l, 16, 0, 0);
}

// non-temporal reads for the once-used 192 MB W stream (R7/R8 verified:
// 2.87 -> 3.74 TB/s logical). Stores stay normal (allocating).
__device__ __forceinline__ f32x4 ntld4(const float* p) {
  return __builtin_nontemporal_load((const f32x4*)p);
}

// ---------------------------------------------------------------------------
// Prep: x fp32 -> bf16 (xs, L2-resident during GEMM); bias precompute.
// ---------------------------------------------------------------------------
__global__ __launch_bounds__(256) void prep_kernel(
    const float* __restrict__ x,
    const float* __restrict__ bmu,
    const float* __restrict__ blv,
    const float* __restrict__ beps,
    u32x4* __restrict__ xs4,
    float* __restrict__ bias)
{
  const uint32_t b = blockIdx.x;
  if (b < 512u) {
    const uint32_t c = b * 256u + threadIdx.x;
    const float* p = x + (size_t)c * 8u;
    f32x4 v0 = ntld4(p);
    f32x4 v1 = ntld4(p + 4);
    u32x4 o;
    o[0] = pack2bf(v0[0], v0[1]); o[1] = pack2bf(v0[2], v0[3]);
    o[2] = pack2bf(v1[0], v1[1]); o[3] = pack2bf(v1[2], v1[3]);
    xs4[c] = o;
  } else {
    const uint32_t i = (b - 512u) * 256u + threadIdx.x;
    bias[i] = fmaf(beps[i], exp2f(blv[i] * HLG), bmu[i]);
  }
}

// ---------------------------------------------------------------------------
// Fused single-pass variational GEMM (R9):
//   R3's validated skeleton (16 cols x 256 rows x K/NSPLIT per WG, 4 waves,
//   LDS bf16 tile + swizzle + fragment addressing + partials epilogue), with
//   - W staged via REGISTERS using nt loads (3 x f32x4/thread/tile),
//     distance-1 ping-pong (A/B register sets, static indexing),
//   - ONE raw s_barrier per iter with lgkmcnt(0) only: W prefetch vmem loads
//     stay in flight across the barrier (no vmcnt(0) drain).
//   Safety: each wave's lgkmcnt(0) before the barrier covers its CVT
//   ds_writes AND its previous COMP ds_reads, so overwriting buf[t&1] at
//   distance 2 can never race a straggler's reads.
//   Program order per iter: LOADS(t+1) FIRST, then COMP's xs loads -> the
//   compiler's dependency waits resolve to vmcnt(3), preserving prefetch.
// ---------------------------------------------------------------------------
template<int NSPLIT>
__global__ __launch_bounds__(256, 4)
void vgemm_fused(const uint16_t* __restrict__ xs,
                 const float*    __restrict__ wmu,
                 const float*    __restrict__ wlv,
                 const float*    __restrict__ weps,
                 const float*    __restrict__ biasp,
                 float*          __restrict__ out)
{
  __shared__ __align__(16) uint8_t bfl[2][2048];   // 2 x (16 rows x 128 B)

  const int tid = threadIdx.x;
  const int wv  = tid >> 6;
  const int l   = tid & 63;
  const int col_tile = blockIdx.x / NSPLIT;
  const int ks       = blockIdx.x % NSPLIT;
  const int n0  = col_tile * 16;
  const int k0  = ks * (IN_F / NSPLIT);
  const int NT  = (IN_F / NSPLIT) / 64;        // 16 for NSPLIT=4

  // --- W load address: thread owns tile elements [tid*4 .. tid*4+3]
  //     (row tid>>4, cols (tid&15)*4 ..): row-major within the 16x64 tile.
  const size_t wbase = (size_t)(n0 + (tid >> 4)) * IN_F + k0 + ((tid & 15) << 2);

  // --- CVT write address (R3 validated)
  const int cr = tid >> 4;
  const int ci = tid & 15;
  const int bfw = cr * 128 + ((((ci >> 1) ^ (cr & 7)) << 4)) + ((ci & 1) << 3);

  // --- fragment addressing (R3 validated)
  const int br = l & 15;
  const int kb = l >> 4;
  const int bfo0 = br * 128 + ((((0 * 4 + kb)) ^ (br & 7)) << 4);
  const int bfo1 = br * 128 + ((((1 * 4 + kb)) ^ (br & 7)) << 4);
  const int arow0 = wv * 64 + br;

  f32x4 acc[4] = {{0,0,0,0},{0,0,0,0},{0,0,0,0},{0,0,0,0}};

  f32x4 mA, vA, eA, mB, vB, eB;   // ping-pong register sets (static names)

#define WLOADS(M,V,E,t) do {                         \
    const size_t _o = wbase + (size_t)(t) * 64;      \
    M = ntld4(wmu + _o);                             \
    V = ntld4(wlv + _o);                             \
    E = ntld4(weps + _o);                            \
  } while (0)

#define WCVT(buf, M, V, E) do {                                       \
    u32x2 _o;                                                         \
    _o[0] = pack2bf(fmaf(E[0], exp2f(V[0]*HLG), M[0]),                \
                    fmaf(E[1], exp2f(V[1]*HLG), M[1]));               \
    _o[1] = pack2bf(fmaf(E[2], exp2f(V[2]*HLG), M[2]),                \
                    fmaf(E[3], exp2f(V[3]*HLG), M[3]));               \
    *(u32x2*)(&bfl[buf][bfw]) = _o;                                   \
  } while (0)

  auto COMP = [&](int t, int buf) {
    bf16x8 b0 = *(const bf16x8*)(&bfl[buf][bfo0]);
    bf16x8 b1 = *(const bf16x8*)(&bfl[buf][bfo1]);
    const size_t kk = (size_t)k0 + (size_t)t * 64 + kb * 8;
#pragma unroll
    for (int j = 0; j < 4; ++j) {
      const uint16_t* xp = xs + (size_t)(arow0 + 16 * j) * IN_F + kk;
      bf16x8 a0 = *(const bf16x8*)(xp);
      bf16x8 a1 = *(const bf16x8*)(xp + 32);
      acc[j] = MFMA(a0, b0, acc[j]);
      acc[j] = MFMA(a1, b1, acc[j]);
    }
  };

  // ---- pipelined main loop (NT even; unrolled x2, static reg sets)
  WLOADS(mA, vA, eA, 0);
  for (int t = 0; t < NT; t += 2) {
    { // even iter: regs A -> buf0; prefetch t+1 -> B
      if (t + 1 < NT) WLOADS(mB, vB, eB, t + 1);
      WCVT(0, mA, vA, eA);
      asm volatile("s_waitcnt lgkmcnt(0)" ::: "memory");
      __builtin_amdgcn_s_barrier();
      COMP(t, 0);
    }
    { // odd iter: regs B -> buf1; prefetch t+2 -> A
      if (t + 2 < NT) WLOADS(mA, vA, eA, t + 2);
      WCVT(1, mB, vB, eB);
      asm volatile("s_waitcnt lgkmcnt(0)" ::: "memory");
      __builtin_amdgcn_s_barrier();
      COMP(t + 1, 1);
    }
  }
#undef WLOADS
#undef WCVT

  // ---- epilogue (R3 validated): D[row=(l>>4)*4+i][col=l&15]
  const int col = n0 + br;
  if constexpr (NSPLIT == 1) {
    const float bv = biasp[col];
#pragma unroll
    for (int j = 0; j < 4; ++j) {
      const int rbase = wv * 64 + j * 16 + kb * 4;
#pragma unroll
      for (int i = 0; i < 4; ++i)
        out[(size_t)(rbase + i) * OUT_F + col] = acc[j][i] + bv;
    }
  } else {
    float* po = out + (size_t)ks * BATCH * OUT_F;
#pragma unroll
    for (int j = 0; j < 4; ++j) {
      const int rbase = wv * 64 + j * 16 + kb * 4;
#pragma unroll
      for (int i = 0; i < 4; ++i)
        po[(size_t)(rbase + i) * OUT_F + col] = acc[j][i];
    }
  }
}

// ---------------------------------------------------------------------------
__global__ __launch_bounds__(256) void reduce_kernel(
    const float* __restrict__ parts,
    const float* __restrict__ bias,
    float* __restrict__ y)
{
  const size_t e = ((size_t)blockIdx.x * 256 + threadIdx.x) * 4;
  f32x4 s = *(const f32x4*)(parts + e);
#pragma unroll
  for (int p = 1; p < KSPLIT; ++p)
    s += *(const f32x4*)(parts + (size_t)p * BATCH * OUT_F + e);
  s += *(const f32x4*)(bias + (e & (OUT_F - 1)));
  *(f32x4*)(y + e) = s;
}

// ---------------------------------------------------------------------------
// Fallback fused GEMM (R3 structure, validated) for degraded ws sizes.
// ---------------------------------------------------------------------------
#define RAW_BUF   12288
#define RAW_ARR   4096
#define BF_BASE   24576
#define LDS_TOTAL 26624

template<int NSPLIT, bool USE_XS>
__global__ __launch_bounds__(256, 4)
void vgemm3(const uint16_t* __restrict__ xs,
            const float*    __restrict__ xf,
            const float*    __restrict__ wmu,
            const float*    __restrict__ wlv,
            const float*    __restrict__ weps,
            const float*    __restrict__ biasp,
            const float*    __restrict__ bmu,
            const float*    __restrict__ blv,
            const float*    __restrict__ beps,
            float*          __restrict__ out)
{
  __shared__ __align__(16) uint8_t lds[LDS_TOTAL];

  const int tid = threadIdx.x;
  const int wv  = tid >> 6;
  const int l   = tid & 63;
  const int col_tile = blockIdx.x / NSPLIT;
  const int ks       = blockIdx.x % NSPLIT;
  const int n0  = col_tile * 16;
  const int k0  = ks * (IN_F / NSPLIT);
  const int NT  = (IN_F / NSPLIT) / 64;

  const size_t sgoff = (size_t)(n0 + 4 * wv + (l >> 4)) * IN_F + k0 + ((l & 15) << 2);
  const int cr = tid >> 4;
  const int ci = tid & 15;
  const int bfw = cr * 128 + ((((ci >> 1) ^ (cr & 7)) << 4)) + ((ci & 1) << 3);
  const int br = l & 15;
  const int kb = l >> 4;
  const int bfo0 = br * 128 + ((((0 * 4 + kb)) ^ (br & 7)) << 4);
  const int bfo1 = br * 128 + ((((1 * 4 + kb)) ^ (br & 7)) << 4);
  const int arow0 = wv * 64 + br;

  f32x4 acc[4] = {{0,0,0,0},{0,0,0,0},{0,0,0,0},{0,0,0,0}};

  auto STAGE = [&](int t, int buf) {
    const size_t go = sgoff + (size_t)t * 64;
    uint8_t* base = &lds[0] + buf * RAW_BUF + wv * 1024;
    gload_lds16(wmu  + go, base + 0 * RAW_ARR);
    gload_lds16(wlv  + go, base + 1 * RAW_ARR);
    gload_lds16(weps + go, base + 2 * RAW_ARR);
  };
  auto CVT = [&](int buf) {
    const uint8_t* rb = &lds[0] + buf * RAW_BUF;
    f32x4 m = *(const f32x4*)(rb + 0 * RAW_ARR + tid * 16);
    f32x4 v = *(const f32x4*)(rb + 1 * RAW_ARR + tid * 16);
    f32x4 e = *(const f32x4*)(rb + 2 * RAW_ARR + tid * 16);
    u32x2 o;
    o[0] = pack2bf(fmaf(e[0], exp2f(v[0] * HLG), m[0]),
                   fmaf(e[1], exp2f(v[1] * HLG), m[1]));
    o[1] = pack2bf(fmaf(e[2], exp2f(v[2] * HLG), m[2]),
                   fmaf(e[3], exp2f(v[3] * HLG), m[3]));
    *(u32x2*)(&lds[0] + BF_BASE + bfw) = o;
  };
  auto COMP = [&](int t) {
    const uint8_t* bfb = &lds[0] + BF_BASE;
    bf16x8 b0 = *(const bf16x8*)(bfb + bfo0);
    bf16x8 b1 = *(const bf16x8*)(bfb + bfo1);
    const size_t kb0 = (size_t)k0 + t * 64 + kb * 8;
#pragma unroll
    for (int j = 0; j < 4; ++j) {
      bf16x8 a0, a1;
      if constexpr (USE_XS) {
        const uint16_t* xp = xs + (size_t)(arow0 + 16 * j) * IN_F + kb0;
        a0 = *(const bf16x8*)(xp);
        a1 = *(const bf16x8*)(xp + 32);
      } else {
        const float* xp = xf + (size_t)(arow0 + 16 * j) * IN_F + kb0;
        a0 = cvt8(xp);
        a1 = cvt8(xp + 32);
      }
      acc[j] = MFMA(a0, b0, acc[j]);
      acc[j] = MFMA(a1, b1, acc[j]);
    }
  };

  STAGE(0, 0);
  for (int t = 0; t < NT; ++t) {
    if (t + 1 < NT) STAGE(t + 1, (t + 1) & 1);
    __syncthreads();
    CVT(t & 1);
    __syncthreads();
    COMP(t);
  }

  const int col = n0 + br;
  if constexpr (NSPLIT == 1) {
    float bv;
    if constexpr (USE_XS) bv = biasp[col];
    else bv = fmaf(beps[col], exp2f(blv[col] * HLG), bmu[col]);
#pragma unroll
    for (int j = 0; j < 4; ++j) {
      const int rbase = wv * 64 + j * 16 + kb * 4;
#pragma unroll
      for (int i = 0; i < 4; ++i)
        out[(size_t)(rbase + i) * OUT_F + col] = acc[j][i] + bv;
    }
  } else {
    float* po = out + (size_t)ks * BATCH * OUT_F;
#pragma unroll
    for (int j = 0; j < 4; ++j) {
      const int rbase = wv * 64 + j * 16 + kb * 4;
#pragma unroll
      for (int i = 0; i < 4; ++i)
        po[(size_t)(rbase + i) * OUT_F + col] = acc[j][i];
    }
  }
}

// ---------------------------------------------------------------------------
extern "C" void kernel_launch(void* const* d_in, const int* in_sizes, int n_in,
                              void* d_out, int out_size, void* d_ws, size_t ws_size,
                              hipStream_t stream) {
  const float* x    = (const float*)d_in[0];
  const float* wmu  = (const float*)d_in[1];
  const float* wlv  = (const float*)d_in[2];
  const float* bmu  = (const float*)d_in[3];
  const float* blv  = (const float*)d_in[4];
  const float* weps = (const float*)d_in[5];
  const float* beps = (const float*)d_in[6];
  float* y = (float*)d_out;

  const size_t xs_b   = (size_t)BATCH * IN_F * 2;            // 2 MiB
  const size_t bias_b = (size_t)OUT_F * 4;                   // 16 KiB
  const size_t part_b = (size_t)KSPLIT * BATCH * OUT_F * 4;  // 16 MiB

  uint16_t* xsp  = (uint16_t*)d_ws;
  float*    bias = (float*)((char*)d_ws + xs_b);

  if (d_ws && ws_size >= xs_b + bias_b + part_b) {
    float* parts = (float*)((char*)d_ws + xs_b + bias_b);
    prep_kernel<<<528, 256, 0, stream>>>(x, bmu, blv, beps, (u32x4*)d_ws, bias);
    vgemm_fused<KSPLIT><<<(OUT_F / 16) * KSPLIT, 256, 0, stream>>>(
        xsp, wmu, wlv, weps, bias, parts);
    reduce_kernel<<<(BATCH * OUT_F) / (256 * 4), 256, 0, stream>>>(parts, bias, y);
  } else if (d_ws && ws_size >= xs_b + bias_b) {
    prep_kernel<<<528, 256, 0, stream>>>(x, bmu, blv, beps, (u32x4*)d_ws, bias);
    vgemm_fused<1><<<OUT_F / 16, 256, 0, stream>>>(
        xsp, wmu, wlv, weps, bias, y);
  } else {
    vgemm3<1, false><<<OUT_F / 16, 256, 0, stream>>>(
        nullptr, x, wmu, wlv, weps, nullptr, bmu, blv, beps, y);
  }
}